// Round 20
// baseline (70.354 us; speedup 1.0000x reference)
//
#include <hip/hip_runtime.h>

// LBP for semantic dependency parsing — label-difference form, all 3
// iterations fused, u-SPACE chain in PRODUCT FORM, hybrid F storage
// (tiles 0-3 in registers, 4-7 in LDS fp16), 2 blocks/CU, pressure-shaped
// loops (r19: VGPR=28, zero spill, 63.4 us).
//
// r20 deltas (stay under the ~32-reg spill tier mapped in r15-r19):
//   - NREG 3->4: +3 VGPR, LDS-F 60->48 KB, -20% pass-2/3 ds_reads
//   - pass-1 tail '#pragma unroll 2': two 6-load tile batches in flight
//     (r19's unroll-1 tail exposed ~half the load latency); pass-2/3
//     tails stay unroll-1 (pure LDS+ALU, nothing to hide)
//
//   F[b,i,j,k] = e^s  (F:=1 for masked/diagonal elements -> u==1 -> zero
//   contribution through ALL passes; no per-pass guards)
//   l = log2(PROD_x (p_x+F_x)) - log2(PROD_x (1+p_x)),
//   p_x = F_x*m + c from wave-uniform constants (one fma each)
//   q_t[k] = q0[k] + mask[k]*sum_i l_t[i,k];  out[b,k,j] = sigmoid(q_3[k])
// Exponent clamp +30: num <= 2^115, no overflow; clamp-bind error <= 2e-7.
//
// Geometry: block (b,j), 1024 thr, 16 waves. Thread = (lane -> k in
// {2*lane, 2*lane+1}, wave wv -> row 16r+wv of tile r, r=0..7).
// fp16 F precision proven r7-r19 (absmax 0.0078 vs threshold 0.02).

#define TS 128
#define SS (TS * TS)
#define NREG 4          // tiles 0..3 in registers; 4..7 in LDS

typedef float    f2v __attribute__((ext_vector_type(2)));
typedef _Float16 h2v __attribute__((ext_vector_type(2)));

constexpr float LOG2E = 1.4426950408889634f;

__device__ __forceinline__ float rcpf(float x)   { return __builtin_amdgcn_rcpf(x); }
__device__ __forceinline__ float clampe(float e) { return fminf(fmaxf(e, -126.0f), 30.0f); }
__device__ __forceinline__ float rfl(float x) {   // wave-uniform value -> SGPR
    return __int_as_float(__builtin_amdgcn_readfirstlane(__float_as_int(x)));
}

// ---- single-block mask format probe: f[0]!=0 byte mask, f[1]!=0 f32, else i32
__global__ void mask_probe(const unsigned char* __restrict__ m, int n, int* __restrict__ f) {
    __shared__ int s1, s23;
    if (threadIdx.x == 0) { s1 = 0; s23 = 0; }
    __syncthreads();
    unsigned a1 = 0, a23 = 0;
    const int n16 = n >> 4;
    const uint4* m4 = (const uint4*)m;
    for (int i = threadIdx.x; i < n16; i += 1024) {
        const uint4 v = m4[i];
        const unsigned o = v.x | v.y | v.z | v.w;
        a1  |= o & 0x0000FF00u;
        a23 |= o & 0xFFFF0000u;
    }
    for (int i = (n16 << 4) + threadIdx.x; i < n; i += 1024) {  // tail bytes
        const unsigned char b = m[i];
        const int r = i & 3;
        if (r == 1) a1 |= b;
        if (r >= 2) a23 |= b;
    }
    if (__any(a1 != 0)  && (threadIdx.x & 63) == 0) atomicOr(&s1, 1);
    if (__any(a23 != 0) && (threadIdx.x & 63) == 0) atomicOr(&s23, 1);
    __syncthreads();
    if (threadIdx.x == 0) { f[0] = s1; f[1] = s23; }
}

__global__ __launch_bounds__(1024, 8)
__attribute__((amdgpu_waves_per_eu(8, 8)))
void lbp_fused(const float* __restrict__ s_edge,
               const float* __restrict__ sib,
               const float* __restrict__ cop,
               const float* __restrict__ grd,
               const void* __restrict__ mask,
               const int* __restrict__ flags,
               float* __restrict__ outp)
{
    __shared__ _Float16 FLs[8 - NREG][16][TS];   // 16 KB each: F tiles 4..7
    __shared__ _Float16 FLc[8 - NREG][16][TS];
    __shared__ _Float16 FLg[8 - NREG][16][TS];
    __shared__ float red[16][TS];                // 8 KB: [wave][k]
    __shared__ float q0s[TS], p1s[TS], r1s[TS], lp3s[TS], g1s[TS], g2s[TS];
    __shared__ unsigned char mrow[TS];

    const int bj = blockIdx.x;
    const int b  = bj >> 7;
    const int j  = bj & (TS - 1);
    const int t  = threadIdx.x;
    const int lane = t & 63;            // k = 2*lane, 2*lane+1
    const int wv = t >> 6;              // wave 0..15; tile r -> row 16r+wv
    const int ka = 2 * lane, kb = 2 * lane + 1;

    // ---- per-column prologue ----
    if (t < TS) {
        const int i = t;
        const int idx = (b * TS + i) * TS + j;
        const float q0 = LOG2E * s_edge[idx];
        q0s[i] = q0;
        const int f1 = flags[0], f23 = flags[1];
        unsigned char mv;
        if (f1)       mv = ((const unsigned char*)mask)[idx] != 0;
        else if (f23) mv = ((const float*)mask)[idx] != 0.0f;
        else          mv = ((const int*)mask)[idx]   != 0;
        mrow[i] = mv;
        const float p1 = exp2f(clampe(-q0));
        p1s[i]  = p1;
        r1s[i]  = rcpf(1.0f + p1);
        lp3s[i] = 3.0f * __log2f(1.0f + p1);
    }
    __syncthreads();

    // per-lane element base of (b, row0=wv, j, 2*lane)
    const size_t gbase = (size_t)b * (TS * SS) + (size_t)j * TS + (size_t)wv * SS + ka;

    h2v Fs[NREG], Fc[NREG], Fg[NREG];
    float a0 = 0.0f, a1 = 0.0f;

    // ---- pass 1, head: tiles 0..3 -> register F (compile-time indices) ----
    #pragma unroll
    for (int r = 0; r < NREG; ++r) {
        const size_t g = gbase + (size_t)(16 * r) * SS;
        const f2v vs = *(const f2v*)(sib + g);
        const f2v vc = *(const f2v*)(cop + g);
        const f2v vg = *(const f2v*)(grd + g);
        const int i = 16 * r + wv;                 // wave-uniform row
        const bool live = (mrow[i] != 0) && (i != j);
        f2v fs, fc, fg;
        #pragma unroll
        for (int c = 0; c < 2; ++c) {
            const bool on = live && (i != ka + c);
            fs[c] = on ? exp2f(LOG2E * vs[c]) : 1.0f;
            fc[c] = on ? exp2f(LOG2E * vc[c]) : 1.0f;
            fg[c] = on ? exp2f(LOG2E * vg[c]) : 1.0f;
        }
        Fs[r] = __builtin_convertvector(fs, h2v);
        Fc[r] = __builtin_convertvector(fc, h2v);
        Fg[r] = __builtin_convertvector(fg, h2v);
        const float p1 = rfl(p1s[i]), lp3 = rfl(lp3s[i]);
        a0 += __log2f((p1 + fs[0]) * (p1 + fc[0]) * (p1 + fg[0])) - lp3;
        a1 += __log2f((p1 + fs[1]) * (p1 + fc[1]) * (p1 + fg[1])) - lp3;
    }
    // ---- pass 1, tail: tiles 4..7 -> LDS F (unroll 2: two load batches) ----
    #pragma unroll 2
    for (int r = NREG; r < 8; ++r) {
        const size_t g = gbase + (size_t)(16 * r) * SS;
        const f2v vs = *(const f2v*)(sib + g);
        const f2v vc = *(const f2v*)(cop + g);
        const f2v vg = *(const f2v*)(grd + g);
        const int i = 16 * r + wv;
        const bool live = (mrow[i] != 0) && (i != j);
        f2v fs, fc, fg;
        #pragma unroll
        for (int c = 0; c < 2; ++c) {
            const bool on = live && (i != ka + c);
            fs[c] = on ? exp2f(LOG2E * vs[c]) : 1.0f;
            fc[c] = on ? exp2f(LOG2E * vc[c]) : 1.0f;
            fg[c] = on ? exp2f(LOG2E * vg[c]) : 1.0f;
        }
        *(h2v*)&FLs[r - NREG][wv][ka] = __builtin_convertvector(fs, h2v);
        *(h2v*)&FLc[r - NREG][wv][ka] = __builtin_convertvector(fc, h2v);
        *(h2v*)&FLg[r - NREG][wv][ka] = __builtin_convertvector(fg, h2v);
        const float p1 = rfl(p1s[i]), lp3 = rfl(lp3s[i]);
        a0 += __log2f((p1 + fs[0]) * (p1 + fc[0]) * (p1 + fg[0])) - lp3;
        a1 += __log2f((p1 + fs[1]) * (p1 + fc[1]) * (p1 + fg[1])) - lp3;
    }

    // reduce -> q1 -> g1  (each (wv,k) partial unique: direct store)
    { f2v v; v[0] = a0; v[1] = a1; *(f2v*)&red[wv][ka] = v; }
    __syncthreads();
    if (t < TS) {
        float tot = 0.0f;
        #pragma unroll
        for (int w = 0; w < 16; ++w) tot += red[w][t];
        const float q1 = q0s[t] + (mrow[t] ? tot : 0.0f);
        g1s[t] = exp2f(clampe(-q1));
    }
    __syncthreads();

    // ---- pass 2: product form, ZERO rcp ----
    a0 = 0.0f; a1 = 0.0f;
    #pragma unroll
    for (int r = 0; r < NREG; ++r) {
        const int i = 16 * r + wv;
        const float m1  = rfl(r1s[i]) * rfl(g1s[i]);
        const float c1  = rfl(p1s[i]) * m1;
        const float m1p = 1.0f + m1;
        const float c1p = 1.0f + c1;
        const f2v fs = __builtin_convertvector(Fs[r], f2v);
        const f2v fc = __builtin_convertvector(Fc[r], f2v);
        const f2v fg = __builtin_convertvector(Fg[r], f2v);
        #pragma unroll
        for (int c = 0; c < 2; ++c) {
            const float as = fmaf(fs[c], m1p, c1), bs = fmaf(fs[c], m1, c1p);
            const float ac = fmaf(fc[c], m1p, c1), bc = fmaf(fc[c], m1, c1p);
            const float ag = fmaf(fg[c], m1p, c1), bg = fmaf(fg[c], m1, c1p);
            const float l = __log2f(as * ac * ag) - __log2f(bs * bc * bg);
            if (c == 0) a0 += l; else a1 += l;
        }
    }
    #pragma unroll 1
    for (int r = NREG; r < 8; ++r) {
        const int i = 16 * r + wv;
        const float m1  = rfl(r1s[i]) * rfl(g1s[i]);
        const float c1  = rfl(p1s[i]) * m1;
        const float m1p = 1.0f + m1;
        const float c1p = 1.0f + c1;
        const f2v fs = __builtin_convertvector(*(const h2v*)&FLs[r - NREG][wv][ka], f2v);
        const f2v fc = __builtin_convertvector(*(const h2v*)&FLc[r - NREG][wv][ka], f2v);
        const f2v fg = __builtin_convertvector(*(const h2v*)&FLg[r - NREG][wv][ka], f2v);
        #pragma unroll
        for (int c = 0; c < 2; ++c) {
            const float as = fmaf(fs[c], m1p, c1), bs = fmaf(fs[c], m1, c1p);
            const float ac = fmaf(fc[c], m1p, c1), bc = fmaf(fc[c], m1, c1p);
            const float ag = fmaf(fg[c], m1p, c1), bg = fmaf(fg[c], m1, c1p);
            const float l = __log2f(as * ac * ag) - __log2f(bs * bc * bg);
            if (c == 0) a0 += l; else a1 += l;
        }
    }

    // reduce -> q2 -> g2
    { f2v v; v[0] = a0; v[1] = a1; *(f2v*)&red[wv][ka] = v; }
    __syncthreads();
    if (t < TS) {
        float tot = 0.0f;
        #pragma unroll
        for (int w = 0; w < 16; ++w) tot += red[w][t];
        const float q2 = q0s[t] + (mrow[t] ? tot : 0.0f);
        g2s[t] = exp2f(clampe(-q2));
    }
    __syncthreads();

    // ---- pass 3: u2 = ax*rcp(bx) (3 rcp), then product form again ----
    a0 = 0.0f; a1 = 0.0f;
    #pragma unroll
    for (int r = 0; r < NREG; ++r) {
        const int i = 16 * r + wv;
        const float m1  = rfl(r1s[i]) * rfl(g1s[i]);
        const float c1  = rfl(p1s[i]) * m1;
        const float m1p = 1.0f + m1;
        const float c1p = 1.0f + c1;
        const float g2  = rfl(g2s[i]);
        const f2v fs = __builtin_convertvector(Fs[r], f2v);
        const f2v fc = __builtin_convertvector(Fc[r], f2v);
        const f2v fg = __builtin_convertvector(Fg[r], f2v);
        #pragma unroll
        for (int c = 0; c < 2; ++c) {
            const float us = fmaf(fs[c], m1p, c1) * rcpf(fmaf(fs[c], m1, c1p));
            const float uc = fmaf(fc[c], m1p, c1) * rcpf(fmaf(fc[c], m1, c1p));
            const float ug = fmaf(fg[c], m1p, c1) * rcpf(fmaf(fg[c], m1, c1p));
            const float ps = us * g2, pc = uc * g2, pg = ug * g2;
            const float l = __log2f((ps + fs[c]) * (pc + fc[c]) * (pg + fg[c]))
                          - __log2f((1.0f + ps) * (1.0f + pc) * (1.0f + pg));
            if (c == 0) a0 += l; else a1 += l;
        }
    }
    #pragma unroll 1
    for (int r = NREG; r < 8; ++r) {
        const int i = 16 * r + wv;
        const float m1  = rfl(r1s[i]) * rfl(g1s[i]);
        const float c1  = rfl(p1s[i]) * m1;
        const float m1p = 1.0f + m1;
        const float c1p = 1.0f + c1;
        const float g2  = rfl(g2s[i]);
        const f2v fs = __builtin_convertvector(*(const h2v*)&FLs[r - NREG][wv][ka], f2v);
        const f2v fc = __builtin_convertvector(*(const h2v*)&FLc[r - NREG][wv][ka], f2v);
        const f2v fg = __builtin_convertvector(*(const h2v*)&FLg[r - NREG][wv][ka], f2v);
        #pragma unroll
        for (int c = 0; c < 2; ++c) {
            const float us = fmaf(fs[c], m1p, c1) * rcpf(fmaf(fs[c], m1, c1p));
            const float uc = fmaf(fc[c], m1p, c1) * rcpf(fmaf(fc[c], m1, c1p));
            const float ug = fmaf(fg[c], m1p, c1) * rcpf(fmaf(fg[c], m1, c1p));
            const float ps = us * g2, pc = uc * g2, pg = ug * g2;
            const float l = __log2f((ps + fs[c]) * (pc + fc[c]) * (pg + fg[c]))
                          - __log2f((1.0f + ps) * (1.0f + pc) * (1.0f + pg));
            if (c == 0) a0 += l; else a1 += l;
        }
    }

    // reduce -> q3 -> output
    { f2v v; v[0] = a0; v[1] = a1; *(f2v*)&red[wv][ka] = v; }
    __syncthreads();
    if (t < TS) {
        float tot = 0.0f;
        #pragma unroll
        for (int w = 0; w < 16; ++w) tot += red[w][t];
        const float q3 = q0s[t] + (mrow[t] ? tot : 0.0f);
        outp[(b * TS + t) * TS + j] = 1.0f / (1.0f + exp2f(clampe(-q3)));
    }
}

extern "C" void kernel_launch(void* const* d_in, const int* in_sizes, int n_in,
                              void* d_out, int out_size, void* d_ws, size_t ws_size,
                              hipStream_t stream) {
    const float* s_edge = (const float*)d_in[0];
    const float* sib    = (const float*)d_in[1];
    const float* cop    = (const float*)d_in[2];
    const float* grd    = (const float*)d_in[3];
    const void*  mask   = d_in[4];
    float* out = (float*)d_out;

    const int Bn = in_sizes[0] / (TS * TS);   // batch
    const int nMask = in_sizes[4];            // B*S*S elements

    int* flags = (int*)d_ws;

    mask_probe<<<1, 1024, 0, stream>>>((const unsigned char*)mask, nMask, flags);
    lbp_fused<<<Bn * TS, 1024, 0, stream>>>(s_edge, sib, cop, grd, mask, flags, out);
}

// Round 21
// 63.384 us; speedup vs baseline: 1.1100x; 1.1100x over previous
//
#include <hip/hip_runtime.h>

// LBP for semantic dependency parsing — label-difference form, all 3
// iterations fused, u-SPACE chain in PRODUCT FORM, hybrid F storage
// (tiles 0-2 in registers, 3-7 in LDS fp16), 2 blocks/CU, pressure-shaped
// loops. THIS IS THE r19 CONFIGURATION (63.4 us, VGPR=28, zero spill) —
// r20's probe (NREG=4 + unroll-2 tail, demand ~36-40) confirmed the
// 32-VGPR tier is a hard wall: allocator pins 32 and spills (dur 70.4).
// Neighbors all mapped worse: NREG=2 breaks the 80 KB/block LDS budget
// for 2 blocks/CU; u2-caching, register-staged MLP, LDS-DMA all spill or
// add issue volume. r19 = local optimum of {reg tier, LDS, occ, unroll}.
//
//   F[b,i,j,k] = e^s  (F:=1 for masked/diagonal elements -> u==1 -> zero
//   contribution through ALL passes; no per-pass guards)
//   l = log2(PROD_x (p_x+F_x)) - log2(PROD_x (1+p_x)),
//   p_x = F_x*m + c from wave-uniform constants (one fma each)
//   q_t[k] = q0[k] + mask[k]*sum_i l_t[i,k];  out[b,k,j] = sigmoid(q_3[k])
// Exponent clamp +30: num <= 2^115, no overflow; clamp-bind error <= 2e-7.
//
// Geometry: block (b,j), 1024 thr, 16 waves. Thread = (lane -> k in
// {2*lane, 2*lane+1}, wave wv -> row 16r+wv of tile r, r=0..7).
// fp16 F precision proven r7-r20 (absmax 0.0078 vs threshold 0.02).

#define TS 128
#define SS (TS * TS)
#define NREG 3          // tiles 0..2 in registers; 3..7 in LDS

typedef float    f2v __attribute__((ext_vector_type(2)));
typedef _Float16 h2v __attribute__((ext_vector_type(2)));

constexpr float LOG2E = 1.4426950408889634f;

__device__ __forceinline__ float rcpf(float x)   { return __builtin_amdgcn_rcpf(x); }
__device__ __forceinline__ float clampe(float e) { return fminf(fmaxf(e, -126.0f), 30.0f); }
__device__ __forceinline__ float rfl(float x) {   // wave-uniform value -> SGPR
    return __int_as_float(__builtin_amdgcn_readfirstlane(__float_as_int(x)));
}

// ---- single-block mask format probe: f[0]!=0 byte mask, f[1]!=0 f32, else i32
__global__ void mask_probe(const unsigned char* __restrict__ m, int n, int* __restrict__ f) {
    __shared__ int s1, s23;
    if (threadIdx.x == 0) { s1 = 0; s23 = 0; }
    __syncthreads();
    unsigned a1 = 0, a23 = 0;
    const int n16 = n >> 4;
    const uint4* m4 = (const uint4*)m;
    for (int i = threadIdx.x; i < n16; i += 1024) {
        const uint4 v = m4[i];
        const unsigned o = v.x | v.y | v.z | v.w;
        a1  |= o & 0x0000FF00u;
        a23 |= o & 0xFFFF0000u;
    }
    for (int i = (n16 << 4) + threadIdx.x; i < n; i += 1024) {  // tail bytes
        const unsigned char b = m[i];
        const int r = i & 3;
        if (r == 1) a1 |= b;
        if (r >= 2) a23 |= b;
    }
    if (__any(a1 != 0)  && (threadIdx.x & 63) == 0) atomicOr(&s1, 1);
    if (__any(a23 != 0) && (threadIdx.x & 63) == 0) atomicOr(&s23, 1);
    __syncthreads();
    if (threadIdx.x == 0) { f[0] = s1; f[1] = s23; }
}

__global__ __launch_bounds__(1024, 8)
__attribute__((amdgpu_waves_per_eu(8, 8)))
void lbp_fused(const float* __restrict__ s_edge,
               const float* __restrict__ sib,
               const float* __restrict__ cop,
               const float* __restrict__ grd,
               const void* __restrict__ mask,
               const int* __restrict__ flags,
               float* __restrict__ outp)
{
    __shared__ _Float16 FLs[8 - NREG][16][TS];   // 20 KB each: F tiles 3..7
    __shared__ _Float16 FLc[8 - NREG][16][TS];
    __shared__ _Float16 FLg[8 - NREG][16][TS];
    __shared__ float red[16][TS];                // 8 KB: [wave][k]
    __shared__ float q0s[TS], p1s[TS], r1s[TS], lp3s[TS], g1s[TS], g2s[TS];
    __shared__ unsigned char mrow[TS];

    const int bj = blockIdx.x;
    const int b  = bj >> 7;
    const int j  = bj & (TS - 1);
    const int t  = threadIdx.x;
    const int lane = t & 63;            // k = 2*lane, 2*lane+1
    const int wv = t >> 6;              // wave 0..15; tile r -> row 16r+wv
    const int ka = 2 * lane, kb = 2 * lane + 1;

    // ---- per-column prologue ----
    if (t < TS) {
        const int i = t;
        const int idx = (b * TS + i) * TS + j;
        const float q0 = LOG2E * s_edge[idx];
        q0s[i] = q0;
        const int f1 = flags[0], f23 = flags[1];
        unsigned char mv;
        if (f1)       mv = ((const unsigned char*)mask)[idx] != 0;
        else if (f23) mv = ((const float*)mask)[idx] != 0.0f;
        else          mv = ((const int*)mask)[idx]   != 0;
        mrow[i] = mv;
        const float p1 = exp2f(clampe(-q0));
        p1s[i]  = p1;
        r1s[i]  = rcpf(1.0f + p1);
        lp3s[i] = 3.0f * __log2f(1.0f + p1);
    }
    __syncthreads();

    // per-lane element base of (b, row0=wv, j, 2*lane)
    const size_t gbase = (size_t)b * (TS * SS) + (size_t)j * TS + (size_t)wv * SS + ka;

    h2v Fs[NREG], Fc[NREG], Fg[NREG];
    float a0 = 0.0f, a1 = 0.0f;

    // ---- pass 1, head: tiles 0..2 -> register F (compile-time indices) ----
    #pragma unroll
    for (int r = 0; r < NREG; ++r) {
        const size_t g = gbase + (size_t)(16 * r) * SS;
        const f2v vs = *(const f2v*)(sib + g);
        const f2v vc = *(const f2v*)(cop + g);
        const f2v vg = *(const f2v*)(grd + g);
        const int i = 16 * r + wv;                 // wave-uniform row
        const bool live = (mrow[i] != 0) && (i != j);
        f2v fs, fc, fg;
        #pragma unroll
        for (int c = 0; c < 2; ++c) {
            const bool on = live && (i != ka + c);
            fs[c] = on ? exp2f(LOG2E * vs[c]) : 1.0f;
            fc[c] = on ? exp2f(LOG2E * vc[c]) : 1.0f;
            fg[c] = on ? exp2f(LOG2E * vg[c]) : 1.0f;
        }
        Fs[r] = __builtin_convertvector(fs, h2v);
        Fc[r] = __builtin_convertvector(fc, h2v);
        Fg[r] = __builtin_convertvector(fg, h2v);
        const float p1 = rfl(p1s[i]), lp3 = rfl(lp3s[i]);
        a0 += __log2f((p1 + fs[0]) * (p1 + fc[0]) * (p1 + fg[0])) - lp3;
        a1 += __log2f((p1 + fs[1]) * (p1 + fc[1]) * (p1 + fg[1])) - lp3;
    }
    // ---- pass 1, tail: tiles 3..7 -> LDS F (runtime addressing, unroll 1) ----
    #pragma unroll 1
    for (int r = NREG; r < 8; ++r) {
        const size_t g = gbase + (size_t)(16 * r) * SS;
        const f2v vs = *(const f2v*)(sib + g);
        const f2v vc = *(const f2v*)(cop + g);
        const f2v vg = *(const f2v*)(grd + g);
        const int i = 16 * r + wv;
        const bool live = (mrow[i] != 0) && (i != j);
        f2v fs, fc, fg;
        #pragma unroll
        for (int c = 0; c < 2; ++c) {
            const bool on = live && (i != ka + c);
            fs[c] = on ? exp2f(LOG2E * vs[c]) : 1.0f;
            fc[c] = on ? exp2f(LOG2E * vc[c]) : 1.0f;
            fg[c] = on ? exp2f(LOG2E * vg[c]) : 1.0f;
        }
        *(h2v*)&FLs[r - NREG][wv][ka] = __builtin_convertvector(fs, h2v);
        *(h2v*)&FLc[r - NREG][wv][ka] = __builtin_convertvector(fc, h2v);
        *(h2v*)&FLg[r - NREG][wv][ka] = __builtin_convertvector(fg, h2v);
        const float p1 = rfl(p1s[i]), lp3 = rfl(lp3s[i]);
        a0 += __log2f((p1 + fs[0]) * (p1 + fc[0]) * (p1 + fg[0])) - lp3;
        a1 += __log2f((p1 + fs[1]) * (p1 + fc[1]) * (p1 + fg[1])) - lp3;
    }

    // reduce -> q1 -> g1  (each (wv,k) partial unique: direct store)
    { f2v v; v[0] = a0; v[1] = a1; *(f2v*)&red[wv][ka] = v; }
    __syncthreads();
    if (t < TS) {
        float tot = 0.0f;
        #pragma unroll
        for (int w = 0; w < 16; ++w) tot += red[w][t];
        const float q1 = q0s[t] + (mrow[t] ? tot : 0.0f);
        g1s[t] = exp2f(clampe(-q1));
    }
    __syncthreads();

    // ---- pass 2: product form, ZERO rcp ----
    a0 = 0.0f; a1 = 0.0f;
    #pragma unroll
    for (int r = 0; r < NREG; ++r) {
        const int i = 16 * r + wv;
        const float m1  = rfl(r1s[i]) * rfl(g1s[i]);
        const float c1  = rfl(p1s[i]) * m1;
        const float m1p = 1.0f + m1;
        const float c1p = 1.0f + c1;
        const f2v fs = __builtin_convertvector(Fs[r], f2v);
        const f2v fc = __builtin_convertvector(Fc[r], f2v);
        const f2v fg = __builtin_convertvector(Fg[r], f2v);
        #pragma unroll
        for (int c = 0; c < 2; ++c) {
            const float as = fmaf(fs[c], m1p, c1), bs = fmaf(fs[c], m1, c1p);
            const float ac = fmaf(fc[c], m1p, c1), bc = fmaf(fc[c], m1, c1p);
            const float ag = fmaf(fg[c], m1p, c1), bg = fmaf(fg[c], m1, c1p);
            const float l = __log2f(as * ac * ag) - __log2f(bs * bc * bg);
            if (c == 0) a0 += l; else a1 += l;
        }
    }
    #pragma unroll 1
    for (int r = NREG; r < 8; ++r) {
        const int i = 16 * r + wv;
        const float m1  = rfl(r1s[i]) * rfl(g1s[i]);
        const float c1  = rfl(p1s[i]) * m1;
        const float m1p = 1.0f + m1;
        const float c1p = 1.0f + c1;
        const f2v fs = __builtin_convertvector(*(const h2v*)&FLs[r - NREG][wv][ka], f2v);
        const f2v fc = __builtin_convertvector(*(const h2v*)&FLc[r - NREG][wv][ka], f2v);
        const f2v fg = __builtin_convertvector(*(const h2v*)&FLg[r - NREG][wv][ka], f2v);
        #pragma unroll
        for (int c = 0; c < 2; ++c) {
            const float as = fmaf(fs[c], m1p, c1), bs = fmaf(fs[c], m1, c1p);
            const float ac = fmaf(fc[c], m1p, c1), bc = fmaf(fc[c], m1, c1p);
            const float ag = fmaf(fg[c], m1p, c1), bg = fmaf(fg[c], m1, c1p);
            const float l = __log2f(as * ac * ag) - __log2f(bs * bc * bg);
            if (c == 0) a0 += l; else a1 += l;
        }
    }

    // reduce -> q2 -> g2
    { f2v v; v[0] = a0; v[1] = a1; *(f2v*)&red[wv][ka] = v; }
    __syncthreads();
    if (t < TS) {
        float tot = 0.0f;
        #pragma unroll
        for (int w = 0; w < 16; ++w) tot += red[w][t];
        const float q2 = q0s[t] + (mrow[t] ? tot : 0.0f);
        g2s[t] = exp2f(clampe(-q2));
    }
    __syncthreads();

    // ---- pass 3: u2 = ax*rcp(bx) (3 rcp), then product form again ----
    a0 = 0.0f; a1 = 0.0f;
    #pragma unroll
    for (int r = 0; r < NREG; ++r) {
        const int i = 16 * r + wv;
        const float m1  = rfl(r1s[i]) * rfl(g1s[i]);
        const float c1  = rfl(p1s[i]) * m1;
        const float m1p = 1.0f + m1;
        const float c1p = 1.0f + c1;
        const float g2  = rfl(g2s[i]);
        const f2v fs = __builtin_convertvector(Fs[r], f2v);
        const f2v fc = __builtin_convertvector(Fc[r], f2v);
        const f2v fg = __builtin_convertvector(Fg[r], f2v);
        #pragma unroll
        for (int c = 0; c < 2; ++c) {
            const float us = fmaf(fs[c], m1p, c1) * rcpf(fmaf(fs[c], m1, c1p));
            const float uc = fmaf(fc[c], m1p, c1) * rcpf(fmaf(fc[c], m1, c1p));
            const float ug = fmaf(fg[c], m1p, c1) * rcpf(fmaf(fg[c], m1, c1p));
            const float ps = us * g2, pc = uc * g2, pg = ug * g2;
            const float l = __log2f((ps + fs[c]) * (pc + fc[c]) * (pg + fg[c]))
                          - __log2f((1.0f + ps) * (1.0f + pc) * (1.0f + pg));
            if (c == 0) a0 += l; else a1 += l;
        }
    }
    #pragma unroll 1
    for (int r = NREG; r < 8; ++r) {
        const int i = 16 * r + wv;
        const float m1  = rfl(r1s[i]) * rfl(g1s[i]);
        const float c1  = rfl(p1s[i]) * m1;
        const float m1p = 1.0f + m1;
        const float c1p = 1.0f + c1;
        const float g2  = rfl(g2s[i]);
        const f2v fs = __builtin_convertvector(*(const h2v*)&FLs[r - NREG][wv][ka], f2v);
        const f2v fc = __builtin_convertvector(*(const h2v*)&FLc[r - NREG][wv][ka], f2v);
        const f2v fg = __builtin_convertvector(*(const h2v*)&FLg[r - NREG][wv][ka], f2v);
        #pragma unroll
        for (int c = 0; c < 2; ++c) {
            const float us = fmaf(fs[c], m1p, c1) * rcpf(fmaf(fs[c], m1, c1p));
            const float uc = fmaf(fc[c], m1p, c1) * rcpf(fmaf(fc[c], m1, c1p));
            const float ug = fmaf(fg[c], m1p, c1) * rcpf(fmaf(fg[c], m1, c1p));
            const float ps = us * g2, pc = uc * g2, pg = ug * g2;
            const float l = __log2f((ps + fs[c]) * (pc + fc[c]) * (pg + fg[c]))
                          - __log2f((1.0f + ps) * (1.0f + pc) * (1.0f + pg));
            if (c == 0) a0 += l; else a1 += l;
        }
    }

    // reduce -> q3 -> output
    { f2v v; v[0] = a0; v[1] = a1; *(f2v*)&red[wv][ka] = v; }
    __syncthreads();
    if (t < TS) {
        float tot = 0.0f;
        #pragma unroll
        for (int w = 0; w < 16; ++w) tot += red[w][t];
        const float q3 = q0s[t] + (mrow[t] ? tot : 0.0f);
        outp[(b * TS + t) * TS + j] = 1.0f / (1.0f + exp2f(clampe(-q3)));
    }
}

extern "C" void kernel_launch(void* const* d_in, const int* in_sizes, int n_in,
                              void* d_out, int out_size, void* d_ws, size_t ws_size,
                              hipStream_t stream) {
    const float* s_edge = (const float*)d_in[0];
    const float* sib    = (const float*)d_in[1];
    const float* cop    = (const float*)d_in[2];
    const float* grd    = (const float*)d_in[3];
    const void*  mask   = d_in[4];
    float* out = (float*)d_out;

    const int Bn = in_sizes[0] / (TS * TS);   // batch
    const int nMask = in_sizes[4];            // B*S*S elements

    int* flags = (int*)d_ws;

    mask_probe<<<1, 1024, 0, stream>>>((const unsigned char*)mask, nMask, flags);
    lbp_fused<<<Bn * TS, 1024, 0, stream>>>(s_edge, sib, cop, grd, mask, flags, out);
}